// Round 2
// baseline (168.309 us; speedup 1.0000x reference)
//
#include <hip/hip_runtime.h>

#define NN 8192
#define DD 128
// ALPHA * log2(e)
#define C2 72.13475204444817f
#define LN2 0.6931471805599453f

typedef __attribute__((ext_vector_type(8))) __bf16 bf16x8;
typedef __attribute__((ext_vector_type(4))) float f32x4;

#if __has_builtin(__builtin_amdgcn_exp2f)
#define EXP2F(x) __builtin_amdgcn_exp2f(x)
#else
#define EXP2F(x) exp2f(x)
#endif
#if __has_builtin(__builtin_amdgcn_sqrtf)
#define SQRTF(x) __builtin_amdgcn_sqrtf(x)
#else
#define SQRTF(x) sqrtf(x)
#endif
#if __has_builtin(__builtin_amdgcn_logf)
#define LOG2F(x) __builtin_amdgcn_logf(x)
#else
#define LOG2F(x) log2f(x)
#endif

__device__ __forceinline__ unsigned short f2bf(float f) {
  unsigned u = __float_as_uint(f);
  u += 0x7FFFu + ((u >> 16) & 1u);  // RNE
  return (unsigned short)(u >> 16);
}

// ------- kernel A: fused bf16-convert + row norms + exact fp32 positives ----
// block = 512 threads = 8 waves = one class (targets are arange(N)//8).
// Also zeroes tot_e (each block its 8 rows) and scal (block 0) so no memset
// dispatch is needed.
__global__ __launch_bounds__(512) void prep_pos_kernel(
    const float* __restrict__ x, unsigned short* __restrict__ xbf,
    float* __restrict__ sq, float* __restrict__ pos_e,
    float* __restrict__ pos_d, float* __restrict__ tot_e,
    float* __restrict__ scal) {
  int w = threadIdx.x >> 6;    // wave = row within class
  int lane = threadIdx.x & 63;
  int i = blockIdx.x * 8 + w;

  __shared__ float xs[8][128];
  __shared__ float sqs[8];

  const float* xr = x + (size_t)i * DD;
  float a = xr[lane], b = xr[lane + 64];
  xs[w][lane] = a;
  xs[w][lane + 64] = b;

  float s = __fmaf_rn(a, a, b * b);
#pragma unroll
  for (int m = 32; m; m >>= 1) s += __shfl_xor(s, m, 64);
  if (lane == 0) {
    sq[i] = s;
    sqs[w] = s;
  }
  unsigned short* o = xbf + (size_t)i * DD;
  o[lane] = f2bf(a);
  o[lane + 64] = f2bf(b);
  if (lane == 1) tot_e[i] = 0.f;
  if (blockIdx.x == 0 && threadIdx.x == 0) scal[0] = 0.f;

  __syncthreads();
  float sqi = sqs[w];
  float pe = 0.f, pd = 0.f;
  for (int j = 0; j < 8; ++j) {
    if (j == w) continue;  // wave-uniform
    float dot = __fmaf_rn(a, xs[j][lane], b * xs[j][lane + 64]);
#pragma unroll
    for (int m = 32; m; m >>= 1) dot += __shfl_xor(dot, m, 64);
    float d2 = fmaxf(__fmaf_rn(-2.f, dot, sqi + sqs[j]), 1e-12f);
    float dist = SQRTF(d2);
    pe += EXP2F(__fmaf_rn(dist, -C2, C2));
    pd += dist;
  }
  if (lane == 0) {
    pos_e[i] = pe;
    pos_d[i] = pd;
  }
}

// ---------------- kernel B: MFMA tile kernel -----------------------------
// grid (64, 16): blockIdx.x = 128-row tile, blockIdx.y = 512-col chunk.
// 1024 blocks = 4 blocks/CU = 16 waves/CU (launch_bounds(256,4) caps VGPR
// at 128; measured use is 124). 4 waves per block in 2x2; each wave owns a
// 64x64 tile (4x4 of 16x16x32 MFMA).
__global__ __launch_bounds__(256, 4) void tile_kernel(
    const unsigned short* __restrict__ xbf, const float* __restrict__ sq,
    float* __restrict__ tot_e, float* __restrict__ scal) {
  int lane = threadIdx.x & 63;
  int wave = threadIdx.x >> 6;
  int q = lane >> 4, c = lane & 15;
  int I0 = blockIdx.x * 128 + (wave >> 1) * 64;  // wave row base
  int Jc = blockIdx.y * 512 + (wave & 1) * 64;   // wave col base (chunk)

  // A fragments: A[m = lane&15][k = q*8 + j] -> 16B contiguous per lane
  bf16x8 afrag[4][4];
#pragma unroll
  for (int rb = 0; rb < 4; ++rb) {
    const unsigned short* ap = xbf + (size_t)(I0 + rb * 16 + c) * DD + q * 8;
#pragma unroll
    for (int ks = 0; ks < 4; ++ks)
      afrag[rb][ks] = *(const bf16x8*)(ap + ks * 32);
  }
  float sqi[16];
#pragma unroll
  for (int rb = 0; rb < 4; ++rb)
#pragma unroll
    for (int r = 0; r < 4; ++r)
      sqi[rb * 4 + r] = sq[I0 + rb * 16 + q * 4 + r];

  float tote[16];
#pragma unroll
  for (int k = 0; k < 16; ++k) tote[k] = 0.f;
  float totd = 0.f;

  for (int jt = 0; jt < 4; ++jt) {
    int J0 = Jc + jt * 128;
    f32x4 acc[4][4];
#pragma unroll
    for (int rb = 0; rb < 4; ++rb)
#pragma unroll
      for (int cb = 0; cb < 4; ++cb) acc[rb][cb] = (f32x4){0.f, 0.f, 0.f, 0.f};
#pragma unroll
    for (int ks = 0; ks < 4; ++ks) {
      bf16x8 bfr[4];  // B = X^T, so B-frag loads identically from X rows
#pragma unroll
      for (int cb = 0; cb < 4; ++cb)
        bfr[cb] = *(const bf16x8*)(xbf + (size_t)(J0 + cb * 16 + c) * DD +
                                   ks * 32 + q * 8);
#pragma unroll
      for (int rb = 0; rb < 4; ++rb)
#pragma unroll
        for (int cb = 0; cb < 4; ++cb)
          acc[rb][cb] = __builtin_amdgcn_mfma_f32_16x16x32_bf16(
              afrag[rb][ks], bfr[cb], acc[rb][cb], 0, 0, 0);
    }
    // epilogue: C/D mapping col = lane&15, row = q*4 + reg (m89-verified)
    float sqj[4];
#pragma unroll
    for (int cb = 0; cb < 4; ++cb) sqj[cb] = sq[J0 + cb * 16 + c];
#pragma unroll
    for (int rb = 0; rb < 4; ++rb) {
#pragma unroll
      for (int cb = 0; cb < 4; ++cb) {
        bool diagTile = (I0 + rb * 16) == (J0 + cb * 16);
#pragma unroll
        for (int r = 0; r < 4; ++r) {
          float d2 = fmaxf(
              __fmaf_rn(-2.f, acc[rb][cb][r], sqi[rb * 4 + r] + sqj[cb]),
              1e-12f);
          float dist = SQRTF(d2);
          float ex = EXP2F(__fmaf_rn(dist, -C2, C2));
          if (diagTile && (q * 4 + r) == c) {  // exclude self-pair
            ex = 0.f;
            dist = 0.f;
          }
          tote[rb * 4 + r] += ex;
          totd += dist;
        }
      }
    }
  }

  // reduce row sums across the 16 column-lanes (lane bits 0..3)
#pragma unroll
  for (int k = 0; k < 16; ++k) {
    float v = tote[k];
    v += __shfl_xor(v, 1, 64);
    v += __shfl_xor(v, 2, 64);
    v += __shfl_xor(v, 4, 64);
    v += __shfl_xor(v, 8, 64);
    tote[k] = v;
  }
  if (c == 0) {
#pragma unroll
    for (int rb = 0; rb < 4; ++rb)
#pragma unroll
      for (int r = 0; r < 4; ++r)
        atomicAdd(&tot_e[I0 + rb * 16 + q * 4 + r], tote[rb * 4 + r]);
  }
  // global dist sum: wave reduce -> block reduce -> one atomic per block
#pragma unroll
  for (int m = 32; m; m >>= 1) totd += __shfl_xor(totd, m, 64);
  __shared__ float part[4];
  if (lane == 0) part[wave] = totd;
  __syncthreads();
  if (threadIdx.x == 0)
    atomicAdd(&scal[0], part[0] + part[1] + part[2] + part[3]);
}

// ---------------- kernel C: final scalars --------------------------------
__global__ void fin_kernel(const float* __restrict__ tot_e,
                           const float* __restrict__ pos_e,
                           const float* __restrict__ pos_d,
                           const float* __restrict__ scal,
                           float* __restrict__ out) {
  int tid = threadIdx.x;
  float lsum = 0.f, pdsum = 0.f;
  for (int i = tid; i < NN; i += 256) {
    float p = pos_e[i];
    float t = tot_e[i];
    float denom = __fmaf_rn(0.5f, t - p, p);  // p + 0.5*(tot - p)
    lsum += LOG2F(denom) - LOG2F(p);          // -log(p/(p+neg)) / ln2
    pdsum += pos_d[i];
  }
  __shared__ float s1[256], s2[256];
  s1[tid] = lsum;
  s2[tid] = pdsum;
  __syncthreads();
  for (int w = 128; w; w >>= 1) {
    if (tid < w) {
      s1[tid] += s1[tid + w];
      s2[tid] += s2[tid + w];
    }
    __syncthreads();
  }
  if (tid == 0) {
    out[0] = s1[0] * LN2 / (float)NN;                   // loss
    out[1] = 1.0f;                                      // prec
    out[2] = s2[0] / (float)(NN * 7);                   // pos_d
    out[3] = (scal[0] - s2[0]) / ((float)NN * 8184.f);  // neg_d
  }
}

extern "C" void kernel_launch(void* const* d_in, const int* in_sizes, int n_in,
                              void* d_out, int out_size, void* d_ws,
                              size_t ws_size, hipStream_t stream) {
  const float* x = (const float*)d_in[0];
  float* out = (float*)d_out;
  char* ws = (char*)d_ws;

  unsigned short* xbf = (unsigned short*)ws;       // 2 MB
  float* sq = (float*)(ws + (size_t)NN * DD * 2);  // 32 KB each
  float* tot_e = sq + NN;
  float* pos_e = tot_e + NN;
  float* pos_d = pos_e + NN;
  float* scal = pos_d + NN;  // [0] = total dist sum

  prep_pos_kernel<<<NN / 8, 512, 0, stream>>>(x, xbf, sq, pos_e, pos_d, tot_e,
                                              scal);
  tile_kernel<<<dim3(64, 16), 256, 0, stream>>>(xbf, sq, tot_e, scal);
  fin_kernel<<<1, 256, 0, stream>>>(tot_e, pos_e, pos_d, scal, out);
}

// Round 3
// 121.841 us; speedup vs baseline: 1.3814x; 1.3814x over previous
//
#include <hip/hip_runtime.h>

#define NN 8192
#define DD 128
// ALPHA * log2(e)
#define C2 72.13475204444817f
#define LN2 0.6931471805599453f

typedef __attribute__((ext_vector_type(8))) __bf16 bf16x8;
typedef __attribute__((ext_vector_type(4))) float f32x4;

#if __has_builtin(__builtin_amdgcn_exp2f)
#define EXP2F(x) __builtin_amdgcn_exp2f(x)
#else
#define EXP2F(x) exp2f(x)
#endif
#if __has_builtin(__builtin_amdgcn_sqrtf)
#define SQRTF(x) __builtin_amdgcn_sqrtf(x)
#else
#define SQRTF(x) sqrtf(x)
#endif
#if __has_builtin(__builtin_amdgcn_logf)
#define LOG2F(x) __builtin_amdgcn_logf(x)
#else
#define LOG2F(x) log2f(x)
#endif

__device__ __forceinline__ unsigned short f2bf(float f) {
  unsigned u = __float_as_uint(f);
  u += 0x7FFFu + ((u >> 16) & 1u);  // RNE
  return (unsigned short)(u >> 16);
}

// ------- kernel A: fused bf16-convert + row norms + exact fp32 positives ----
// block = 512 threads = 8 waves = one class (targets are arange(N)//8).
// Also zeroes tot_e (each block its 8 rows) and scal (block 0) so no memset
// dispatch is needed.
__global__ __launch_bounds__(512) void prep_pos_kernel(
    const float* __restrict__ x, unsigned short* __restrict__ xbf,
    float* __restrict__ sq, float* __restrict__ pos_e,
    float* __restrict__ pos_d, float* __restrict__ tot_e,
    float* __restrict__ scal) {
  int w = threadIdx.x >> 6;    // wave = row within class
  int lane = threadIdx.x & 63;
  int i = blockIdx.x * 8 + w;

  __shared__ float xs[8][128];
  __shared__ float sqs[8];

  const float* xr = x + (size_t)i * DD;
  float a = xr[lane], b = xr[lane + 64];
  xs[w][lane] = a;
  xs[w][lane + 64] = b;

  float s = __fmaf_rn(a, a, b * b);
#pragma unroll
  for (int m = 32; m; m >>= 1) s += __shfl_xor(s, m, 64);
  if (lane == 0) {
    sq[i] = s;
    sqs[w] = s;
  }
  unsigned short* o = xbf + (size_t)i * DD;
  o[lane] = f2bf(a);
  o[lane + 64] = f2bf(b);
  if (lane == 1) tot_e[i] = 0.f;
  if (blockIdx.x == 0 && threadIdx.x == 0) scal[0] = 0.f;

  __syncthreads();
  float sqi = sqs[w];
  float pe = 0.f, pd = 0.f;
  for (int j = 0; j < 8; ++j) {
    if (j == w) continue;  // wave-uniform
    float dot = __fmaf_rn(a, xs[j][lane], b * xs[j][lane + 64]);
#pragma unroll
    for (int m = 32; m; m >>= 1) dot += __shfl_xor(dot, m, 64);
    float d2 = fmaxf(__fmaf_rn(-2.f, dot, sqi + sqs[j]), 1e-12f);
    float dist = SQRTF(d2);
    pe += EXP2F(__fmaf_rn(dist, -C2, C2));
    pd += dist;
  }
  if (lane == 0) {
    pos_e[i] = pe;
    pos_d[i] = pd;
  }
}

// ---------------- kernel B: MFMA tile kernel -----------------------------
// grid (64, 16): blockIdx.x = 128-row tile, blockIdx.y = 512-col chunk.
// 1024 blocks; VGPR target ~124 (launch_bounds(256,2) — do NOT force 4:
// that caps VGPR at 64 and spills 300+ MB to scratch, R2 regression).
// 124 VGPR rounds to 128 = 512/4, so HW still achieves 4 blocks/CU.
__global__ __launch_bounds__(256, 2) void tile_kernel(
    const unsigned short* __restrict__ xbf, const float* __restrict__ sq,
    float* __restrict__ tot_e, float* __restrict__ scal) {
  int lane = threadIdx.x & 63;
  int wave = threadIdx.x >> 6;
  int q = lane >> 4, c = lane & 15;
  int I0 = blockIdx.x * 128 + (wave >> 1) * 64;  // wave row base
  int Jc = blockIdx.y * 512 + (wave & 1) * 64;   // wave col base (chunk)

  // A fragments: A[m = lane&15][k = q*8 + j] -> 16B contiguous per lane
  bf16x8 afrag[4][4];
#pragma unroll
  for (int rb = 0; rb < 4; ++rb) {
    const unsigned short* ap = xbf + (size_t)(I0 + rb * 16 + c) * DD + q * 8;
#pragma unroll
    for (int ks = 0; ks < 4; ++ks)
      afrag[rb][ks] = *(const bf16x8*)(ap + ks * 32);
  }
  float sqi[16];
#pragma unroll
  for (int rb = 0; rb < 4; ++rb)
#pragma unroll
    for (int r = 0; r < 4; ++r)
      sqi[rb * 4 + r] = sq[I0 + rb * 16 + q * 4 + r];

  float tote[16];
#pragma unroll
  for (int k = 0; k < 16; ++k) tote[k] = 0.f;
  float totd = 0.f;

  for (int jt = 0; jt < 4; ++jt) {
    int J0 = Jc + jt * 128;
    f32x4 acc[4][4];
#pragma unroll
    for (int rb = 0; rb < 4; ++rb)
#pragma unroll
      for (int cb = 0; cb < 4; ++cb) acc[rb][cb] = (f32x4){0.f, 0.f, 0.f, 0.f};
#pragma unroll
    for (int ks = 0; ks < 4; ++ks) {
      bf16x8 bfr[4];  // B = X^T, so B-frag loads identically from X rows
#pragma unroll
      for (int cb = 0; cb < 4; ++cb)
        bfr[cb] = *(const bf16x8*)(xbf + (size_t)(J0 + cb * 16 + c) * DD +
                                   ks * 32 + q * 8);
#pragma unroll
      for (int rb = 0; rb < 4; ++rb)
#pragma unroll
        for (int cb = 0; cb < 4; ++cb)
          acc[rb][cb] = __builtin_amdgcn_mfma_f32_16x16x32_bf16(
              afrag[rb][ks], bfr[cb], acc[rb][cb], 0, 0, 0);
    }
    // epilogue: C/D mapping col = lane&15, row = q*4 + reg (m89-verified)
    float sqj[4];
#pragma unroll
    for (int cb = 0; cb < 4; ++cb) sqj[cb] = sq[J0 + cb * 16 + c];
#pragma unroll
    for (int rb = 0; rb < 4; ++rb) {
#pragma unroll
      for (int cb = 0; cb < 4; ++cb) {
        bool diagTile = (I0 + rb * 16) == (J0 + cb * 16);
#pragma unroll
        for (int r = 0; r < 4; ++r) {
          float d2 = fmaxf(
              __fmaf_rn(-2.f, acc[rb][cb][r], sqi[rb * 4 + r] + sqj[cb]),
              1e-12f);
          float dist = SQRTF(d2);
          float ex = EXP2F(__fmaf_rn(dist, -C2, C2));
          if (diagTile && (q * 4 + r) == c) {  // exclude self-pair
            ex = 0.f;
            dist = 0.f;
          }
          tote[rb * 4 + r] += ex;
          totd += dist;
        }
      }
    }
  }

  // reduce row sums across the 16 column-lanes (lane bits 0..3)
#pragma unroll
  for (int k = 0; k < 16; ++k) {
    float v = tote[k];
    v += __shfl_xor(v, 1, 64);
    v += __shfl_xor(v, 2, 64);
    v += __shfl_xor(v, 4, 64);
    v += __shfl_xor(v, 8, 64);
    tote[k] = v;
  }
  if (c == 0) {
#pragma unroll
    for (int rb = 0; rb < 4; ++rb)
#pragma unroll
      for (int r = 0; r < 4; ++r)
        atomicAdd(&tot_e[I0 + rb * 16 + q * 4 + r], tote[rb * 4 + r]);
  }
  // global dist sum: wave reduce -> block reduce -> one atomic per block
#pragma unroll
  for (int m = 32; m; m >>= 1) totd += __shfl_xor(totd, m, 64);
  __shared__ float part[4];
  if (lane == 0) part[wave] = totd;
  __syncthreads();
  if (threadIdx.x == 0)
    atomicAdd(&scal[0], part[0] + part[1] + part[2] + part[3]);
}

// ---------------- kernel C: final scalars --------------------------------
__global__ void fin_kernel(const float* __restrict__ tot_e,
                           const float* __restrict__ pos_e,
                           const float* __restrict__ pos_d,
                           const float* __restrict__ scal,
                           float* __restrict__ out) {
  int tid = threadIdx.x;
  float lsum = 0.f, pdsum = 0.f;
  for (int i = tid; i < NN; i += 256) {
    float p = pos_e[i];
    float t = tot_e[i];
    float denom = __fmaf_rn(0.5f, t - p, p);  // p + 0.5*(tot - p)
    lsum += LOG2F(denom) - LOG2F(p);          // -log(p/(p+neg)) / ln2
    pdsum += pos_d[i];
  }
  __shared__ float s1[256], s2[256];
  s1[tid] = lsum;
  s2[tid] = pdsum;
  __syncthreads();
  for (int w = 128; w; w >>= 1) {
    if (tid < w) {
      s1[tid] += s1[tid + w];
      s2[tid] += s2[tid + w];
    }
    __syncthreads();
  }
  if (tid == 0) {
    out[0] = s1[0] * LN2 / (float)NN;                   // loss
    out[1] = 1.0f;                                      // prec
    out[2] = s2[0] / (float)(NN * 7);                   // pos_d
    out[3] = (scal[0] - s2[0]) / ((float)NN * 8184.f);  // neg_d
  }
}

extern "C" void kernel_launch(void* const* d_in, const int* in_sizes, int n_in,
                              void* d_out, int out_size, void* d_ws,
                              size_t ws_size, hipStream_t stream) {
  const float* x = (const float*)d_in[0];
  float* out = (float*)d_out;
  char* ws = (char*)d_ws;

  unsigned short* xbf = (unsigned short*)ws;       // 2 MB
  float* sq = (float*)(ws + (size_t)NN * DD * 2);  // 32 KB each
  float* tot_e = sq + NN;
  float* pos_e = tot_e + NN;
  float* pos_d = pos_e + NN;
  float* scal = pos_d + NN;  // [0] = total dist sum

  prep_pos_kernel<<<NN / 8, 512, 0, stream>>>(x, xbf, sq, pos_e, pos_d, tot_e,
                                              scal);
  tile_kernel<<<dim3(64, 16), 256, 0, stream>>>(xbf, sq, tot_e, scal);
  fin_kernel<<<1, 256, 0, stream>>>(tot_e, pos_e, pos_d, scal, out);
}